// Round 5
// baseline (280.040 us; speedup 1.0000x reference)
//
#include <hip/hip_runtime.h>
#include <hip/hip_bf16.h>

#define B_ 4
#define T_ 512
#define N_ 16
#define D_ 256
#define H_ 8
#define DK_ 32
#define NT_ (N_ * T_)
#define CTS_ 6
#define CN_ 4
#define CE_ 3
#define TSE_ 192
#define AUXE_ 64
#define SPLIT_ 8
#define KWORDS_ (NT_ / 64)   // 128 mask words per row

// Q pre-scale: (1/sqrt(32)) * log2(e)  -> MFMA output is already in exp2 domain
#define QSCALE_ 0.2550689747f
// fixed softmax shift (exp2 domain): 8 * log2(e)
#define C2_ 11.5415603f

typedef unsigned long long ull;
typedef __bf16 bf16x8 __attribute__((ext_vector_type(8)));
typedef float f32x4 __attribute__((ext_vector_type(4)));

// ---------------------------------------------------------------- PE table
__global__ __launch_bounds__(256) void pe_kernel(float* pe) {
    int t = blockIdx.x;
    int d = threadIdx.x;
    int j = d >> 1;
    float div = expf((float)(2 * j) * (-9.210340371976184f / 256.0f)); // -ln(10000)/D
    float a = (float)t * div;
    pe[t * D_ + d] = (d & 1) ? cosf(a) : sinf(a);
}

// ------------------------------------- mask -> transposed bitmask [B][128][T]
__global__ __launch_bounds__(256) void maskbits_kernel(const int* __restrict__ mask,
                                                       ull* __restrict__ bitsT) {
    int row = blockIdx.x;  // b*T + t
    int b = row >> 9, t = row & (T_ - 1);
    const int* mrow = mask + (size_t)row * NT_;
    int lane = threadIdx.x & 63, wave = threadIdx.x >> 6;
    for (int it = 0; it < NT_ / 256; ++it) {
        int k = it * 256 + wave * 64 + lane;
        ull bal = __ballot(mrow[k] != 0);
        if (lane == 0) bitsT[((size_t)b * KWORDS_ + (k >> 6)) * T_ + t] = bal;
    }
}

// -------------------------------- weight prep: bf16, fragment-tiled layouts
__global__ __launch_bounds__(256) void wprep_kernel(
    const float* __restrict__ W_ts1, const float* __restrict__ W_a1,
    const float* __restrict__ W_e1, const float* __restrict__ W_ts2,
    const float* __restrict__ W_a2, const float* __restrict__ W_e2,
    const float* __restrict__ Wk, const float* __restrict__ Wv,
    __bf16* __restrict__ ts1P, __bf16* __restrict__ a1P, __bf16* __restrict__ e1P,
    __bf16* __restrict__ ts2T, __bf16* __restrict__ a2T, __bf16* __restrict__ e2T,
    __bf16* __restrict__ WkT, __bf16* __restrict__ WvT) {
    int i = blockIdx.x * 256 + threadIdx.x;
    if (i < 6144) { int col = i >> 5, k = i & 31;
        ts1P[i] = (__bf16)(k < 6 ? W_ts1[k * TSE_ + col] : 0.f); return; }
    i -= 6144;
    if (i < 2048) { int col = i >> 5, k = i & 31;
        a1P[i] = (__bf16)((k >= 6 && k < 10) ? W_a1[(k - 6) * AUXE_ + col] : 0.f); return; }
    i -= 2048;
    if (i < 8192) { int col = i >> 5, k = i & 31;
        e1P[i] = (__bf16)((k >= 10 && k < 13) ? W_e1[(k - 10) * D_ + col] : 0.f); return; }
    i -= 8192;
    if (i < 36864) {  // ts2: COLS=192, KS=6
        int tile = i >> 9, lr = (i >> 5) & 15, kk = i & 31;
        int ct = tile / 6, ks = tile % 6;
        ts2T[i] = (__bf16)W_ts2[(ks * 32 + kk) * TSE_ + ct * 16 + lr]; return; }
    i -= 36864;
    if (i < 4096) {   // a2: COLS=64, KS=2
        int tile = i >> 9, lr = (i >> 5) & 15, kk = i & 31;
        int ct = tile / 2, ks = tile % 2;
        a2T[i] = (__bf16)W_a2[(ks * 32 + kk) * AUXE_ + ct * 16 + lr]; return; }
    i -= 4096;
    if (i < 65536) {  // e2: COLS=256, KS=8
        int tile = i >> 9, lr = (i >> 5) & 15, kk = i & 31;
        int ct = tile >> 3, ks = tile & 7;
        e2T[i] = (__bf16)W_e2[(ks * 32 + kk) * D_ + ct * 16 + lr]; return; }
    i -= 65536;
    if (i < 65536) {  // Wk
        int tile = i >> 9, lr = (i >> 5) & 15, kk = i & 31;
        int ct = tile >> 3, ks = tile & 7;
        WkT[i] = (__bf16)Wk[(ks * 32 + kk) * D_ + ct * 16 + lr]; return; }
    i -= 65536;
    {                 // Wv
        int tile = i >> 9, lr = (i >> 5) & 15, kk = i & 31;
        int ct = tile >> 3, ks = tile & 7;
        WvT[i] = (__bf16)Wv[(ks * 32 + kk) * D_ + ct * 16 + lr]; }
}

// ------------------------- MFMA kv chain: 64 rows/block, 4 waves x 16-row tiles
__global__ __launch_bounds__(256, 2) void kv_mfma_kernel(
    const float* __restrict__ md, const float* __restrict__ na, const float* __restrict__ ea,
    const __bf16* __restrict__ ts1P, const __bf16* __restrict__ a1P,
    const __bf16* __restrict__ e1P,
    const float* __restrict__ b_ts1, const float* __restrict__ b_a1,
    const float* __restrict__ b_e1,
    const __bf16* __restrict__ ts2T, const __bf16* __restrict__ a2T,
    const __bf16* __restrict__ e2T,
    const float* __restrict__ b_ts2, const float* __restrict__ b_a2,
    const float* __restrict__ b_e2,
    const __bf16* __restrict__ WkT, const float* __restrict__ bk,
    const __bf16* __restrict__ WvT, const float* __restrict__ bv,
    const float* __restrict__ pe, __bf16* __restrict__ Kb, __bf16* __restrict__ Vt) {
    int blk = blockIdx.x;          // 4b * 16n * 8t = 512
    int t0 = (blk & 7) * 64;
    int n = (blk >> 3) & 15;
    int b = blk >> 7;
    int tid = threadIdx.x, lane = tid & 63, w = tid >> 6;
    int lr = lane & 15, lg = lane >> 4;

    __shared__ __bf16 sA[64 * 40];      // A_all: 13 channels + zero pad to K=32
    __shared__ __bf16 sU[34304];        // union: {hts,haux,hedge} then {skey,sval}
    __bf16* hts = sU;                   // [64][200]
    __bf16* haux = sU + 12800;          // [64][72]
    __bf16* hedge = sU + 17408;         // [64][264]
    __bf16* skey = sU;                  // [64][264]
    __bf16* sval = sU + 16896;          // [64][264]

    for (int i = tid; i < 64 * 40; i += 256) sA[i] = (__bf16)0.f;
    __syncthreads();
    {
        int t = tid & 63, cg = tid >> 6;
        size_t bn = (size_t)b * N_ + n;
        for (int c = cg; c < 13; c += 4) {
            float v;
            if (c < 6) v = md[(bn * CTS_ + c) * T_ + t0 + t];
            else if (c < 10) v = na[(bn * CN_ + (c - 6)) * T_ + t0 + t];
            else v = ea[(bn * CE_ + (c - 10)) * T_ + t0 + t];
            sA[t * 40 + c] = (__bf16)v;
        }
    }
    __syncthreads();

    int arow = w * 16 + lr;       // A-fragment row
    int crow = w * 16 + lg * 4;   // C-fragment row base (+reg)
    bf16x8 afrag1 = *(const bf16x8*)(sA + arow * 40 + lg * 8);
    int foff = lr * 32 + lg * 8;  // per-lane offset within a 512-elem fragment tile

    // ---- phase 2: first layers (K=32, one MFMA per col-tile), ReLU, store bf16
#pragma unroll 1
    for (int ct = 0; ct < 12; ++ct) {
        int gcol = ct * 16 + lr;
        bf16x8 bf = *(const bf16x8*)(ts1P + ct * 512 + foff);
        f32x4 z = {0.f, 0.f, 0.f, 0.f};
        f32x4 c = __builtin_amdgcn_mfma_f32_16x16x32_bf16(afrag1, bf, z, 0, 0, 0);
        float bias = b_ts1[gcol];
#pragma unroll
        for (int r = 0; r < 4; ++r) hts[(crow + r) * 200 + gcol] = (__bf16)fmaxf(c[r] + bias, 0.f);
    }
#pragma unroll 1
    for (int ct = 0; ct < 4; ++ct) {
        int gcol = ct * 16 + lr;
        bf16x8 bf = *(const bf16x8*)(a1P + ct * 512 + foff);
        f32x4 z = {0.f, 0.f, 0.f, 0.f};
        f32x4 c = __builtin_amdgcn_mfma_f32_16x16x32_bf16(afrag1, bf, z, 0, 0, 0);
        float bias = b_a1[gcol];
#pragma unroll
        for (int r = 0; r < 4; ++r) haux[(crow + r) * 72 + gcol] = (__bf16)fmaxf(c[r] + bias, 0.f);
    }
#pragma unroll 1
    for (int ct = 0; ct < 16; ++ct) {
        int gcol = ct * 16 + lr;
        bf16x8 bf = *(const bf16x8*)(e1P + ct * 512 + foff);
        f32x4 z = {0.f, 0.f, 0.f, 0.f};
        f32x4 c = __builtin_amdgcn_mfma_f32_16x16x32_bf16(afrag1, bf, z, 0, 0, 0);
        float bias = b_e1[gcol];
#pragma unroll
        for (int r = 0; r < 4; ++r) hedge[(crow + r) * 264 + gcol] = (__bf16)fmaxf(c[r] + bias, 0.f);
    }
    __syncthreads();

    // ---- phase 3: nbr (ts2|a2) and edg (e2) accumulators in registers
    f32x4 nacc[16], eacc[16];
#pragma unroll
    for (int ct = 0; ct < 16; ++ct) {
        nacc[ct] = (f32x4){0.f, 0.f, 0.f, 0.f};
        eacc[ct] = (f32x4){0.f, 0.f, 0.f, 0.f};
    }
#pragma unroll 1
    for (int ks = 0; ks < 8; ++ks) {
        bf16x8 af = *(const bf16x8*)(hedge + arow * 264 + ks * 32 + lg * 8);
#pragma unroll
        for (int ct = 0; ct < 16; ++ct) {
            bf16x8 bf = *(const bf16x8*)(e2T + (ct * 8 + ks) * 512 + foff);
            eacc[ct] = __builtin_amdgcn_mfma_f32_16x16x32_bf16(af, bf, eacc[ct], 0, 0, 0);
        }
    }
#pragma unroll 1
    for (int ks = 0; ks < 6; ++ks) {
        bf16x8 af = *(const bf16x8*)(hts + arow * 200 + ks * 32 + lg * 8);
#pragma unroll
        for (int ct = 0; ct < 12; ++ct) {
            bf16x8 bf = *(const bf16x8*)(ts2T + (ct * 6 + ks) * 512 + foff);
            nacc[ct] = __builtin_amdgcn_mfma_f32_16x16x32_bf16(af, bf, nacc[ct], 0, 0, 0);
        }
    }
#pragma unroll
    for (int ks = 0; ks < 2; ++ks) {
        bf16x8 af = *(const bf16x8*)(haux + arow * 72 + ks * 32 + lg * 8);
#pragma unroll
        for (int ct = 0; ct < 4; ++ct) {
            bf16x8 bf = *(const bf16x8*)(a2T + (ct * 2 + ks) * 512 + foff);
            nacc[12 + ct] = __builtin_amdgcn_mfma_f32_16x16x32_bf16(af, bf, nacc[12 + ct], 0, 0, 0);
        }
    }
    __syncthreads();   // hts/haux/hedge reads done; safe to overwrite union

    // ---- phase 3b: key = nbr*edg + pe, val = nbr + pe (bf16 into LDS)
#pragma unroll
    for (int ct = 0; ct < 16; ++ct) {
        int gcol = ct * 16 + lr;
        float nb_bias = (ct < 12) ? b_ts2[gcol] : b_a2[gcol - 192];
        float ed_bias = b_e2[gcol];
#pragma unroll
        for (int r = 0; r < 4; ++r) {
            int row = crow + r;
            float p = pe[(t0 + row) * D_ + gcol];
            float nb = nacc[ct][r] + nb_bias;
            float ed = eacc[ct][r] + ed_bias;
            skey[row * 264 + gcol] = (__bf16)(nb * ed + p);
            sval[row * 264 + gcol] = (__bf16)(nb + p);
        }
    }
    __syncthreads();

    // ---- phase 4: K/V projections (K=256 -> 8 ksteps per col-tile)
    size_t key0 = (size_t)n * T_ + t0;
#pragma unroll 1
    for (int ct = 0; ct < 16; ++ct) {
        int gcol = ct * 16 + lr;
        f32x4 ka = {0.f, 0.f, 0.f, 0.f}, va = {0.f, 0.f, 0.f, 0.f};
#pragma unroll
        for (int ks = 0; ks < 8; ++ks) {
            bf16x8 afk = *(const bf16x8*)(skey + arow * 264 + ks * 32 + lg * 8);
            bf16x8 afv = *(const bf16x8*)(sval + arow * 264 + ks * 32 + lg * 8);
            bf16x8 b8k = *(const bf16x8*)(WkT + (ct * 8 + ks) * 512 + foff);
            bf16x8 b8v = *(const bf16x8*)(WvT + (ct * 8 + ks) * 512 + foff);
            ka = __builtin_amdgcn_mfma_f32_16x16x32_bf16(afk, b8k, ka, 0, 0, 0);
            va = __builtin_amdgcn_mfma_f32_16x16x32_bf16(afv, b8v, va, 0, 0, 0);
        }
        float kbias = bk[gcol], vbias = bv[gcol];
        int h = gcol >> 5, dd = gcol & 31;
        size_t bh = (size_t)b * H_ + h;
#pragma unroll
        for (int r = 0; r < 4; ++r)
            Kb[(bh * NT_ + key0 + crow + r) * DK_ + dd] = (__bf16)(ka[r] + kbias);
        __bf16 tmp[4];
#pragma unroll
        for (int r = 0; r < 4; ++r) tmp[r] = (__bf16)(va[r] + vbias);
        *(ushort4*)(Vt + (bh * DK_ + dd) * NT_ + key0 + crow) = *(ushort4*)tmp;
    }
}

// -------------------------- xq = x + pe, LayerNorm, Q proj -> bf16 Qb (pre-scaled)
__global__ __launch_bounds__(256) void q_kernel(
    const float* __restrict__ x, const float* __restrict__ pe,
    const float* __restrict__ Wq, const float* __restrict__ bq,
    const float* __restrict__ ln_g, const float* __restrict__ ln_b,
    float* __restrict__ xq, __bf16* __restrict__ Qb) {
    int blk = blockIdx.x;
    int t0 = (blk & 31) * 16;
    int b = blk >> 5;
    int tid = threadIdx.x;

    __shared__ float s_xn[16][D_];
    __shared__ float s_red[8];

    for (int r = 0; r < 16; ++r) {
        int t = t0 + r;
        size_t off = ((size_t)b * T_ + t) * D_ + tid;
        float v = x[off] + pe[t * D_ + tid];
        xq[off] = v;
        float s1 = v, s2 = v * v;
#pragma unroll
        for (int o = 32; o; o >>= 1) {
            s1 += __shfl_down(s1, o, 64);
            s2 += __shfl_down(s2, o, 64);
        }
        if ((tid & 63) == 0) {
            s_red[tid >> 6] = s1;
            s_red[4 + (tid >> 6)] = s2;
        }
        __syncthreads();
        float t1 = s_red[0] + s_red[1] + s_red[2] + s_red[3];
        float t2 = s_red[4] + s_red[5] + s_red[6] + s_red[7];
        float mu = t1 * (1.f / D_);
        float var = t2 * (1.f / D_) - mu * mu;
        float rs = rsqrtf(var + 1e-6f);
        s_xn[r][tid] = (v - mu) * rs * ln_g[tid] + ln_b[tid];
        __syncthreads();
    }

    float acc[16];
#pragma unroll
    for (int r = 0; r < 16; ++r) acc[r] = bq[tid];
    for (int e = 0; e < D_; ++e) {
        float w = Wq[e * D_ + tid];
#pragma unroll
        for (int r = 0; r < 16; ++r) acc[r] += s_xn[r][e] * w;
    }
    for (int r = 0; r < 16; ++r) {
        Qb[((size_t)b * T_ + t0 + r) * D_ + tid] = (__bf16)(acc[r] * QSCALE_);
    }
}

// ------------------- MFMA flash attention, fixed-max softmax, barrier-free loop
// grid: B*H*(T/64)*SPLIT = 2048 blocks, 256 threads (4 waves x 16 queries)
__global__ __launch_bounds__(256) void attn_mfma_kernel(
    const __bf16* __restrict__ Qb, const __bf16* __restrict__ Kb,
    const __bf16* __restrict__ Vt, const ull* __restrict__ bitsT,
    float* __restrict__ Opart, float* __restrict__ Lpart) {
    int blk = blockIdx.x;
    int kh = blk & (SPLIT_ - 1);
    int qt = (blk >> 3) & 7;
    int h = (blk >> 6) & 7;
    int b = blk >> 9;
    int tid = threadIdx.x, lane = tid & 63, w = tid >> 6;
    int lg = lane >> 4, lr = lane & 15;

    __shared__ __align__(16) __bf16 sP[4 * 16 * 72];   // per-wave P, stride 72

    const size_t bh = (size_t)b * H_ + h;
    const __bf16* Kbase = Kb + bh * NT_ * DK_;
    const __bf16* Vbase = Vt + bh * DK_ * NT_;
    const ull* mbase = bitsT + (size_t)b * KWORDS_ * T_;

    // constant Q fragment (pre-scaled): lane holds Q[qrow][lg*8 .. +8]
    int qrow = qt * 64 + w * 16 + lr;
    bf16x8 qfrag = *(const bf16x8*)(Qb + ((size_t)b * T_ + qrow) * D_ + h * DK_ + lg * 8);

    f32x4 acc0 = {0.f, 0.f, 0.f, 0.f}, acc1 = {0.f, 0.f, 0.f, 0.f};
    float l_lane[4] = {0.f, 0.f, 0.f, 0.f};
    int qglob = qt * 64 + w * 16 + lg * 4;   // + r
    const int TILES = KWORDS_ / SPLIT_;       // 16

#pragma unroll 1
    for (int kt = 0; kt < TILES; ++kt) {
        int ktg = kh * TILES + kt;
        int k0 = ktg * 64;

        // ---- QK^T: 4 MFMAs, fragments direct from global (coalesced, L1/L2-hit)
        f32x4 s4[4];
#pragma unroll
        for (int sub = 0; sub < 4; ++sub) {
            bf16x8 kf = *(const bf16x8*)(Kbase + (size_t)(k0 + sub * 16 + lr) * DK_ + lg * 8);
            f32x4 z = {0.f, 0.f, 0.f, 0.f};
            s4[sub] = __builtin_amdgcn_mfma_f32_16x16x32_bf16(qfrag, kf, z, 0, 0, 0);
        }

        // ---- fixed-max softmax: p = bit ? exp2(s - C2) : 0; accumulate l per-lane
#pragma unroll
        for (int r = 0; r < 4; ++r) {
            ull mw = mbase[(size_t)ktg * T_ + qglob + r] >> lr;
#pragma unroll
            for (int sub = 0; sub < 4; ++sub) {
                float p = ((mw >> (sub * 16)) & 1ull) ? exp2f(s4[sub][r] - C2_) : 0.f;
                l_lane[r] += p;
                sP[w * 1152 + (lg * 4 + r) * 72 + sub * 16 + lr] = (__bf16)p;
            }
        }

        // ---- PV: wave-private sP (no barrier); V fragments direct from global
#pragma unroll
        for (int kstep = 0; kstep < 2; ++kstep) {
            bf16x8 pa = *(const bf16x8*)(sP + w * 1152 + lr * 72 + kstep * 32 + lg * 8);
            bf16x8 vf0 = *(const bf16x8*)(Vbase + (size_t)lr * NT_ + k0 + kstep * 32 + lg * 8);
            acc0 = __builtin_amdgcn_mfma_f32_16x16x32_bf16(pa, vf0, acc0, 0, 0, 0);
            bf16x8 vf1 = *(const bf16x8*)(Vbase + (size_t)(16 + lr) * NT_ + k0 + kstep * 32 + lg * 8);
            acc1 = __builtin_amdgcn_mfma_f32_16x16x32_bf16(pa, vf1, acc1, 0, 0, 0);
        }
    }

    // ---- one-time l reduction across the 16 key-lanes (lr axis = lane bits 0..3)
#pragma unroll
    for (int o = 1; o <= 8; o <<= 1)
#pragma unroll
        for (int r = 0; r < 4; ++r) l_lane[r] += __shfl_xor(l_lane[r], o, 64);

    size_t obase = (((size_t)kh * B_ + b) * H_ + h) * T_ + qt * 64;
    int qloc = w * 16 + lg * 4;
#pragma unroll
    for (int r = 0; r < 4; ++r) {
        Opart[(obase + qloc + r) * DK_ + lr] = acc0[r];
        Opart[(obase + qloc + r) * DK_ + 16 + lr] = acc1[r];
    }
    if (lr == 0) {
#pragma unroll
        for (int r = 0; r < 4; ++r) Lpart[obase + qloc + r] = l_lane[r];
    }
}

// ------------------------------------ merge split-K partials (plain sums) -> ctx
__global__ __launch_bounds__(256) void merge_kernel(
    const float* __restrict__ Opart, const float* __restrict__ Lpart,
    float* __restrict__ ctx) {
    int idx = blockIdx.x * 256 + threadIdx.x;  // B*H*T*32 total
    int d = idx & 31;
    int t = (idx >> 5) & (T_ - 1);
    int bh = idx >> 14;
    int h = bh & 7, b = bh >> 3;
    size_t ps = (size_t)B_ * H_ * T_;
    size_t base = (size_t)bh * T_ + t;
    float L = 0.f, o = 0.f;
#pragma unroll
    for (int s = 0; s < SPLIT_; ++s) {
        L += Lpart[s * ps + base];
        o += Opart[(s * ps + base) * DK_ + d];
    }
    ctx[((size_t)b * T_ + t) * D_ + h * DK_ + d] = o / L;
}

// ------------------------------------------------ out = xq + ctx@Wo + bo
__global__ __launch_bounds__(256) void out_kernel(
    const float* __restrict__ ctx, const float* __restrict__ xq,
    const float* __restrict__ Wo, const float* __restrict__ bo, float* __restrict__ out) {
    int blk = blockIdx.x;
    int t0 = (blk & 31) * 16;
    int b = blk >> 5;
    int tid = threadIdx.x;
    __shared__ float s_c[16][D_];
    for (int r = 0; r < 16; ++r)
        s_c[r][tid] = ctx[((size_t)b * T_ + t0 + r) * D_ + tid];
    __syncthreads();
    float acc[16];
#pragma unroll
    for (int r = 0; r < 16; ++r) acc[r] = bo[tid];
    for (int e = 0; e < D_; ++e) {
        float w = Wo[e * D_ + tid];
#pragma unroll
        for (int r = 0; r < 16; ++r) acc[r] += s_c[r][e] * w;
    }
    for (int r = 0; r < 16; ++r) {
        size_t off = ((size_t)b * T_ + t0 + r) * D_ + tid;
        out[off] = xq[off] + acc[r];
    }
}

// ---------------------------------------------------------------- launcher
extern "C" void kernel_launch(void* const* d_in, const int* in_sizes, int n_in,
                              void* d_out, int out_size, void* d_ws, size_t ws_size,
                              hipStream_t stream) {
    const float* x = (const float*)d_in[0];
    const float* md = (const float*)d_in[1];
    const float* na = (const float*)d_in[2];
    const float* ea = (const float*)d_in[3];
    const int* mask = (const int*)d_in[4];
    const float* W_ts1 = (const float*)d_in[5];
    const float* b_ts1 = (const float*)d_in[6];
    const float* W_ts2 = (const float*)d_in[7];
    const float* b_ts2 = (const float*)d_in[8];
    const float* W_a1 = (const float*)d_in[9];
    const float* b_a1 = (const float*)d_in[10];
    const float* W_a2 = (const float*)d_in[11];
    const float* b_a2 = (const float*)d_in[12];
    const float* W_e1 = (const float*)d_in[13];
    const float* b_e1 = (const float*)d_in[14];
    const float* W_e2 = (const float*)d_in[15];
    const float* b_e2 = (const float*)d_in[16];
    const float* Wq = (const float*)d_in[17];
    const float* bq = (const float*)d_in[18];
    const float* Wk = (const float*)d_in[19];
    const float* bk = (const float*)d_in[20];
    const float* Wv = (const float*)d_in[21];
    const float* bv = (const float*)d_in[22];
    const float* Wo = (const float*)d_in[23];
    const float* bo = (const float*)d_in[24];
    const float* ln_g = (const float*)d_in[25];
    const float* ln_b = (const float*)d_in[26];
    float* out = (float*)d_out;

    char* ws = (char*)d_ws;
    float* pe = (float*)ws;    ws += (size_t)T_ * D_ * 4;
    ull* bitsT = (ull*)ws;     ws += (size_t)B_ * KWORDS_ * T_ * 8;
    __bf16* Kb = (__bf16*)ws;  ws += (size_t)B_ * H_ * NT_ * DK_ * 2;
    __bf16* Vt = (__bf16*)ws;  ws += (size_t)B_ * H_ * DK_ * NT_ * 2;
    float* xq = (float*)ws;    ws += (size_t)B_ * T_ * D_ * 4;
    __bf16* Qb = (__bf16*)ws;  ws += (size_t)B_ * T_ * D_ * 2;
    float* ctx = (float*)ws;   ws += (size_t)B_ * T_ * D_ * 4;
    float* Opart = (float*)ws; ws += (size_t)SPLIT_ * B_ * H_ * T_ * DK_ * 4;
    float* Lpart = (float*)ws; ws += (size_t)SPLIT_ * B_ * H_ * T_ * 4;
    // bf16 prepped weights
    __bf16* ts1P = (__bf16*)ws; ws += 6144 * 2;
    __bf16* a1P = (__bf16*)ws;  ws += 2048 * 2;
    __bf16* e1P = (__bf16*)ws;  ws += 8192 * 2;
    __bf16* ts2T = (__bf16*)ws; ws += 36864 * 2;
    __bf16* a2T = (__bf16*)ws;  ws += 4096 * 2;
    __bf16* e2T = (__bf16*)ws;  ws += 65536 * 2;
    __bf16* WkT = (__bf16*)ws;  ws += 65536 * 2;
    __bf16* WvT = (__bf16*)ws;  ws += 65536 * 2;

    pe_kernel<<<T_, 256, 0, stream>>>(pe);
    maskbits_kernel<<<B_ * T_, 256, 0, stream>>>(mask, bitsT);
    wprep_kernel<<<992, 256, 0, stream>>>(W_ts1, W_a1, W_e1, W_ts2, W_a2, W_e2, Wk, Wv,
                                          ts1P, a1P, e1P, ts2T, a2T, e2T, WkT, WvT);
    kv_mfma_kernel<<<B_ * N_ * (T_ / 64), 256, 0, stream>>>(
        md, na, ea, ts1P, a1P, e1P, b_ts1, b_a1, b_e1,
        ts2T, a2T, e2T, b_ts2, b_a2, b_e2, WkT, bk, WvT, bv, pe, Kb, Vt);
    q_kernel<<<B_ * (T_ / 16), 256, 0, stream>>>(x, pe, Wq, bq, ln_g, ln_b, xq, Qb);
    attn_mfma_kernel<<<B_ * H_ * (T_ / 64) * SPLIT_, 256, 0, stream>>>(
        Qb, Kb, Vt, bitsT, Opart, Lpart);
    merge_kernel<<<(B_ * H_ * T_ * DK_) / 256, 256, 0, stream>>>(Opart, Lpart, ctx);
    out_kernel<<<B_ * (T_ / 16), 256, 0, stream>>>(ctx, xq, Wo, bo, out);
}

// Round 6
// 268.015 us; speedup vs baseline: 1.0449x; 1.0449x over previous
//
#include <hip/hip_runtime.h>
#include <hip/hip_bf16.h>

#define B_ 4
#define T_ 512
#define N_ 16
#define D_ 256
#define H_ 8
#define DK_ 32
#define NT_ (N_ * T_)
#define CTS_ 6
#define CN_ 4
#define CE_ 3
#define TSE_ 192
#define AUXE_ 64
#define SPLIT_ 4
#define KWORDS_ (NT_ / 64)   // 128 mask words per row

// Q pre-scale: (1/sqrt(32)) * log2(e)  -> MFMA output is already in exp2 domain
#define QSCALE_ 0.2550689747f
// fixed softmax shift (exp2 domain): 8 * log2(e)
#define C2_ 11.5415603f

typedef unsigned long long ull;
typedef unsigned int uint;
typedef __bf16 bf16x8 __attribute__((ext_vector_type(8)));
typedef float f32x4 __attribute__((ext_vector_type(4)));

// ---------------------------------------------------------------- PE table
__global__ __launch_bounds__(256) void pe_kernel(float* pe) {
    int t = blockIdx.x;
    int d = threadIdx.x;
    int j = d >> 1;
    float div = expf((float)(2 * j) * (-9.210340371976184f / 256.0f)); // -ln(10000)/D
    float a = (float)t * div;
    pe[t * D_ + d] = (d & 1) ? cosf(a) : sinf(a);
}

// ------------------------------------- mask -> transposed bitmask [B][128][T]
__global__ __launch_bounds__(256) void maskbits_kernel(const int* __restrict__ mask,
                                                       ull* __restrict__ bitsT) {
    int row = blockIdx.x;  // b*T + t
    int b = row >> 9, t = row & (T_ - 1);
    const int* mrow = mask + (size_t)row * NT_;
    int lane = threadIdx.x & 63, wave = threadIdx.x >> 6;
    for (int it = 0; it < NT_ / 256; ++it) {
        int k = it * 256 + wave * 64 + lane;
        ull bal = __ballot(mrow[k] != 0);
        if (lane == 0) bitsT[((size_t)b * KWORDS_ + (k >> 6)) * T_ + t] = bal;
    }
}

// -------------------------------- weight prep: bf16, fragment-tiled layouts
__global__ __launch_bounds__(256) void wprep_kernel(
    const float* __restrict__ W_ts1, const float* __restrict__ W_a1,
    const float* __restrict__ W_e1, const float* __restrict__ W_ts2,
    const float* __restrict__ W_a2, const float* __restrict__ W_e2,
    const float* __restrict__ Wk, const float* __restrict__ Wv,
    __bf16* __restrict__ ts1P, __bf16* __restrict__ a1P, __bf16* __restrict__ e1P,
    __bf16* __restrict__ ts2T, __bf16* __restrict__ a2T, __bf16* __restrict__ e2T,
    __bf16* __restrict__ WkT, __bf16* __restrict__ WvT) {
    int i = blockIdx.x * 256 + threadIdx.x;
    if (i < 6144) { int col = i >> 5, k = i & 31;
        ts1P[i] = (__bf16)(k < 6 ? W_ts1[k * TSE_ + col] : 0.f); return; }
    i -= 6144;
    if (i < 2048) { int col = i >> 5, k = i & 31;
        a1P[i] = (__bf16)((k >= 6 && k < 10) ? W_a1[(k - 6) * AUXE_ + col] : 0.f); return; }
    i -= 2048;
    if (i < 8192) { int col = i >> 5, k = i & 31;
        e1P[i] = (__bf16)((k >= 10 && k < 13) ? W_e1[(k - 10) * D_ + col] : 0.f); return; }
    i -= 8192;
    if (i < 36864) {  // ts2: COLS=192, KS=6
        int tile = i >> 9, lr = (i >> 5) & 15, kk = i & 31;
        int ct = tile / 6, ks = tile % 6;
        ts2T[i] = (__bf16)W_ts2[(ks * 32 + kk) * TSE_ + ct * 16 + lr]; return; }
    i -= 36864;
    if (i < 4096) {   // a2: COLS=64, KS=2
        int tile = i >> 9, lr = (i >> 5) & 15, kk = i & 31;
        int ct = tile / 2, ks = tile % 2;
        a2T[i] = (__bf16)W_a2[(ks * 32 + kk) * AUXE_ + ct * 16 + lr]; return; }
    i -= 4096;
    if (i < 65536) {  // e2: COLS=256, KS=8
        int tile = i >> 9, lr = (i >> 5) & 15, kk = i & 31;
        int ct = tile >> 3, ks = tile & 7;
        e2T[i] = (__bf16)W_e2[(ks * 32 + kk) * D_ + ct * 16 + lr]; return; }
    i -= 65536;
    if (i < 65536) {  // Wk
        int tile = i >> 9, lr = (i >> 5) & 15, kk = i & 31;
        int ct = tile >> 3, ks = tile & 7;
        WkT[i] = (__bf16)Wk[(ks * 32 + kk) * D_ + ct * 16 + lr]; return; }
    i -= 65536;
    {                 // Wv
        int tile = i >> 9, lr = (i >> 5) & 15, kk = i & 31;
        int ct = tile >> 3, ks = tile & 7;
        WvT[i] = (__bf16)Wv[(ks * 32 + kk) * D_ + ct * 16 + lr]; }
}

// ------------------------- MFMA kv chain: 64 rows/block, 4 waves x 16-row tiles
__global__ __launch_bounds__(256, 2) void kv_mfma_kernel(
    const float* __restrict__ md, const float* __restrict__ na, const float* __restrict__ ea,
    const __bf16* __restrict__ ts1P, const __bf16* __restrict__ a1P,
    const __bf16* __restrict__ e1P,
    const float* __restrict__ b_ts1, const float* __restrict__ b_a1,
    const float* __restrict__ b_e1,
    const __bf16* __restrict__ ts2T, const __bf16* __restrict__ a2T,
    const __bf16* __restrict__ e2T,
    const float* __restrict__ b_ts2, const float* __restrict__ b_a2,
    const float* __restrict__ b_e2,
    const __bf16* __restrict__ WkT, const float* __restrict__ bk,
    const __bf16* __restrict__ WvT, const float* __restrict__ bv,
    const float* __restrict__ pe, __bf16* __restrict__ Kb, __bf16* __restrict__ Vt) {
    int blk = blockIdx.x;          // 4b * 16n * 8t = 512
    int t0 = (blk & 7) * 64;
    int n = (blk >> 3) & 15;
    int b = blk >> 7;
    int tid = threadIdx.x, lane = tid & 63, w = tid >> 6;
    int lr = lane & 15, lg = lane >> 4;

    __shared__ __bf16 sA[64 * 40];      // A_all: 13 channels + zero pad to K=32
    __shared__ __bf16 sU[34304];        // union: {hts,haux,hedge} then {skey,sval}
    __bf16* hts = sU;                   // [64][200]
    __bf16* haux = sU + 12800;          // [64][72]
    __bf16* hedge = sU + 17408;         // [64][264]
    __bf16* skey = sU;                  // [64][264]
    __bf16* sval = sU + 16896;          // [64][264]

    for (int i = tid; i < 64 * 40; i += 256) sA[i] = (__bf16)0.f;
    __syncthreads();
    {
        int t = tid & 63, cg = tid >> 6;
        size_t bn = (size_t)b * N_ + n;
        for (int c = cg; c < 13; c += 4) {
            float v;
            if (c < 6) v = md[(bn * CTS_ + c) * T_ + t0 + t];
            else if (c < 10) v = na[(bn * CN_ + (c - 6)) * T_ + t0 + t];
            else v = ea[(bn * CE_ + (c - 10)) * T_ + t0 + t];
            sA[t * 40 + c] = (__bf16)v;
        }
    }
    __syncthreads();

    int arow = w * 16 + lr;       // A-fragment row
    int crow = w * 16 + lg * 4;   // C-fragment row base (+reg)
    bf16x8 afrag1 = *(const bf16x8*)(sA + arow * 40 + lg * 8);
    int foff = lr * 32 + lg * 8;  // per-lane offset within a 512-elem fragment tile

    // ---- phase 2: first layers (K=32, one MFMA per col-tile), ReLU, store bf16
#pragma unroll 1
    for (int ct = 0; ct < 12; ++ct) {
        int gcol = ct * 16 + lr;
        bf16x8 bf = *(const bf16x8*)(ts1P + ct * 512 + foff);
        f32x4 z = {0.f, 0.f, 0.f, 0.f};
        f32x4 c = __builtin_amdgcn_mfma_f32_16x16x32_bf16(afrag1, bf, z, 0, 0, 0);
        float bias = b_ts1[gcol];
#pragma unroll
        for (int r = 0; r < 4; ++r) hts[(crow + r) * 200 + gcol] = (__bf16)fmaxf(c[r] + bias, 0.f);
    }
#pragma unroll 1
    for (int ct = 0; ct < 4; ++ct) {
        int gcol = ct * 16 + lr;
        bf16x8 bf = *(const bf16x8*)(a1P + ct * 512 + foff);
        f32x4 z = {0.f, 0.f, 0.f, 0.f};
        f32x4 c = __builtin_amdgcn_mfma_f32_16x16x32_bf16(afrag1, bf, z, 0, 0, 0);
        float bias = b_a1[gcol];
#pragma unroll
        for (int r = 0; r < 4; ++r) haux[(crow + r) * 72 + gcol] = (__bf16)fmaxf(c[r] + bias, 0.f);
    }
#pragma unroll 1
    for (int ct = 0; ct < 16; ++ct) {
        int gcol = ct * 16 + lr;
        bf16x8 bf = *(const bf16x8*)(e1P + ct * 512 + foff);
        f32x4 z = {0.f, 0.f, 0.f, 0.f};
        f32x4 c = __builtin_amdgcn_mfma_f32_16x16x32_bf16(afrag1, bf, z, 0, 0, 0);
        float bias = b_e1[gcol];
#pragma unroll
        for (int r = 0; r < 4; ++r) hedge[(crow + r) * 264 + gcol] = (__bf16)fmaxf(c[r] + bias, 0.f);
    }
    __syncthreads();

    // ---- phase 3: nbr (ts2|a2) and edg (e2) accumulators in registers
    f32x4 nacc[16], eacc[16];
#pragma unroll
    for (int ct = 0; ct < 16; ++ct) {
        nacc[ct] = (f32x4){0.f, 0.f, 0.f, 0.f};
        eacc[ct] = (f32x4){0.f, 0.f, 0.f, 0.f};
    }
#pragma unroll 1
    for (int ks = 0; ks < 8; ++ks) {
        bf16x8 af = *(const bf16x8*)(hedge + arow * 264 + ks * 32 + lg * 8);
#pragma unroll
        for (int ct = 0; ct < 16; ++ct) {
            bf16x8 bf = *(const bf16x8*)(e2T + (ct * 8 + ks) * 512 + foff);
            eacc[ct] = __builtin_amdgcn_mfma_f32_16x16x32_bf16(af, bf, eacc[ct], 0, 0, 0);
        }
    }
#pragma unroll 1
    for (int ks = 0; ks < 6; ++ks) {
        bf16x8 af = *(const bf16x8*)(hts + arow * 200 + ks * 32 + lg * 8);
#pragma unroll
        for (int ct = 0; ct < 12; ++ct) {
            bf16x8 bf = *(const bf16x8*)(ts2T + (ct * 6 + ks) * 512 + foff);
            nacc[ct] = __builtin_amdgcn_mfma_f32_16x16x32_bf16(af, bf, nacc[ct], 0, 0, 0);
        }
    }
#pragma unroll
    for (int ks = 0; ks < 2; ++ks) {
        bf16x8 af = *(const bf16x8*)(haux + arow * 72 + ks * 32 + lg * 8);
#pragma unroll
        for (int ct = 0; ct < 4; ++ct) {
            bf16x8 bf = *(const bf16x8*)(a2T + (ct * 2 + ks) * 512 + foff);
            nacc[12 + ct] = __builtin_amdgcn_mfma_f32_16x16x32_bf16(af, bf, nacc[12 + ct], 0, 0, 0);
        }
    }
    __syncthreads();   // hts/haux/hedge reads done; safe to overwrite union

    // ---- phase 3b: key = nbr*edg + pe, val = nbr + pe (bf16 into LDS)
#pragma unroll
    for (int ct = 0; ct < 16; ++ct) {
        int gcol = ct * 16 + lr;
        float nb_bias = (ct < 12) ? b_ts2[gcol] : b_a2[gcol - 192];
        float ed_bias = b_e2[gcol];
#pragma unroll
        for (int r = 0; r < 4; ++r) {
            int row = crow + r;
            float p = pe[(t0 + row) * D_ + gcol];
            float nb = nacc[ct][r] + nb_bias;
            float ed = eacc[ct][r] + ed_bias;
            skey[row * 264 + gcol] = (__bf16)(nb * ed + p);
            sval[row * 264 + gcol] = (__bf16)(nb + p);
        }
    }
    __syncthreads();

    // ---- phase 4: K/V projections (K=256 -> 8 ksteps per col-tile)
    size_t key0 = (size_t)n * T_ + t0;
#pragma unroll 1
    for (int ct = 0; ct < 16; ++ct) {
        int gcol = ct * 16 + lr;
        f32x4 ka = {0.f, 0.f, 0.f, 0.f}, va = {0.f, 0.f, 0.f, 0.f};
#pragma unroll
        for (int ks = 0; ks < 8; ++ks) {
            bf16x8 afk = *(const bf16x8*)(skey + arow * 264 + ks * 32 + lg * 8);
            bf16x8 afv = *(const bf16x8*)(sval + arow * 264 + ks * 32 + lg * 8);
            bf16x8 b8k = *(const bf16x8*)(WkT + (ct * 8 + ks) * 512 + foff);
            bf16x8 b8v = *(const bf16x8*)(WvT + (ct * 8 + ks) * 512 + foff);
            ka = __builtin_amdgcn_mfma_f32_16x16x32_bf16(afk, b8k, ka, 0, 0, 0);
            va = __builtin_amdgcn_mfma_f32_16x16x32_bf16(afv, b8v, va, 0, 0, 0);
        }
        float kbias = bk[gcol], vbias = bv[gcol];
        int h = gcol >> 5, dd = gcol & 31;
        size_t bh = (size_t)b * H_ + h;
#pragma unroll
        for (int r = 0; r < 4; ++r)
            Kb[(bh * NT_ + key0 + crow + r) * DK_ + dd] = (__bf16)(ka[r] + kbias);
        __bf16 tmp[4];
#pragma unroll
        for (int r = 0; r < 4; ++r) tmp[r] = (__bf16)(va[r] + vbias);
        *(ushort4*)(Vt + (bh * DK_ + dd) * NT_ + key0 + crow) = *(ushort4*)tmp;
    }
}

// -------------------------- xq = x + pe, LayerNorm, Q proj -> bf16 Qb (pre-scaled)
__global__ __launch_bounds__(256) void q_kernel(
    const float* __restrict__ x, const float* __restrict__ pe,
    const float* __restrict__ Wq, const float* __restrict__ bq,
    const float* __restrict__ ln_g, const float* __restrict__ ln_b,
    float* __restrict__ xq, __bf16* __restrict__ Qb) {
    int blk = blockIdx.x;
    int t0 = (blk & 31) * 16;
    int b = blk >> 5;
    int tid = threadIdx.x;

    __shared__ float s_xn[16][D_];
    __shared__ float s_red[8];

    for (int r = 0; r < 16; ++r) {
        int t = t0 + r;
        size_t off = ((size_t)b * T_ + t) * D_ + tid;
        float v = x[off] + pe[t * D_ + tid];
        xq[off] = v;
        float s1 = v, s2 = v * v;
#pragma unroll
        for (int o = 32; o; o >>= 1) {
            s1 += __shfl_down(s1, o, 64);
            s2 += __shfl_down(s2, o, 64);
        }
        if ((tid & 63) == 0) {
            s_red[tid >> 6] = s1;
            s_red[4 + (tid >> 6)] = s2;
        }
        __syncthreads();
        float t1 = s_red[0] + s_red[1] + s_red[2] + s_red[3];
        float t2 = s_red[4] + s_red[5] + s_red[6] + s_red[7];
        float mu = t1 * (1.f / D_);
        float var = t2 * (1.f / D_) - mu * mu;
        float rs = rsqrtf(var + 1e-6f);
        s_xn[r][tid] = (v - mu) * rs * ln_g[tid] + ln_b[tid];
        __syncthreads();
    }

    float acc[16];
#pragma unroll
    for (int r = 0; r < 16; ++r) acc[r] = bq[tid];
    for (int e = 0; e < D_; ++e) {
        float w = Wq[e * D_ + tid];
#pragma unroll
        for (int r = 0; r < 16; ++r) acc[r] += s_xn[r][e] * w;
    }
    for (int r = 0; r < 16; ++r) {
        Qb[((size_t)b * T_ + t0 + r) * D_ + tid] = (__bf16)(acc[r] * QSCALE_);
    }
}

// ---------------- MFMA attention: swapped QK^T (S^T), in-register P, reg prefetch
// grid: B*H*(T/64)*SPLIT = 1024 blocks, 256 threads (4 waves x 16 queries)
// Per lane after S^T = mfma(K, Q): q = lr (fixed), keys = sub*16 + lg*4 + r.
// P^T B-fragment needs keys = kstep*32 + lg*8 + j: redistribute via shfl:
//   target (lg_t, j) pulls pk[s=kstep*2+(lg_t>>1)][j&1] from lane ((2*lg_t+(j>>1))&3)*16+lr
__global__ __launch_bounds__(256, 4) void attn_mfma_kernel(
    const __bf16* __restrict__ Qb, const __bf16* __restrict__ Kb,
    const __bf16* __restrict__ Vt, const ull* __restrict__ bitsT,
    float* __restrict__ Opart, float* __restrict__ Lpart) {
    int blk = blockIdx.x;
    int kh = blk & (SPLIT_ - 1);
    int qt = (blk >> 2) & 7;
    int h = (blk >> 5) & 7;
    int b = blk >> 8;
    int tid = threadIdx.x, lane = tid & 63, w = tid >> 6;
    int lg = lane >> 4, lr = lane & 15;

    const size_t bh = (size_t)b * H_ + h;
    const int TILES = KWORDS_ / SPLIT_;   // 32

    // Q fragment (B-role): lane holds Q[q=lr][d=lg*8..+8], pre-scaled by QSCALE
    int qrow = qt * 64 + w * 16 + lr;
    bf16x8 qfrag = *(const bf16x8*)(Qb + ((size_t)b * T_ + qrow) * D_ + h * DK_ + lg * 8);

    // running pointers (uniform per-tile advance) + per-lane constant offsets
    const __bf16* kp = Kb + bh * NT_ * DK_ + (size_t)(kh * TILES) * 64 * DK_;
    const __bf16* vp = Vt + bh * DK_ * NT_ + (size_t)(kh * TILES) * 64;
    const ull* mp = bitsT + (size_t)b * KWORDS_ * T_ + (size_t)(kh * TILES) * T_ + qrow;

    int koff[4], voff[4];
#pragma unroll
    for (int s = 0; s < 4; ++s) koff[s] = (s * 16 + lr) * DK_ + lg * 8;
#pragma unroll
    for (int i = 0; i < 4; ++i) voff[i] = ((i >> 1) * 16 + lr) * NT_ + (i & 1) * 32 + lg * 8;
    // shfl source lanes for P redistribution
    int src0 = ((2 * lg) & 3) * 16 + lr;
    int src1 = ((2 * lg + 1) & 3) * 16 + lr;
    bool hiHalf = (lg >= 2);

    f32x4 acc0 = {0.f, 0.f, 0.f, 0.f}, acc1 = {0.f, 0.f, 0.f, 0.f};
    float l_lane = 0.f;

    // preload tile 0 (K frags + mask)
    bf16x8 kc[4];
#pragma unroll
    for (int s = 0; s < 4; ++s) kc[s] = *(const bf16x8*)(kp + koff[s]);
    ull mw = *mp;

#pragma unroll 1
    for (int kt = 0; kt < TILES; ++kt) {
        // issue next-tile K + mask (reads past segment on last iter land in d_ws; unused)
        bf16x8 kn[4];
#pragma unroll
        for (int s = 0; s < 4; ++s) kn[s] = *(const bf16x8*)(kp + 64 * DK_ + koff[s]);
        ull mn = mp[T_];
        // issue current-tile V (consumed at end of iteration)
        bf16x8 vc[4];
#pragma unroll
        for (int i = 0; i < 4; ++i) vc[i] = *(const bf16x8*)(vp + voff[i]);

        // ---- S^T = mfma(K, Q): lane holds S[key=sub*16+lg*4+r][q=lr]
        f32x4 s4[4];
#pragma unroll
        for (int s = 0; s < 4; ++s) {
            f32x4 z = {0.f, 0.f, 0.f, 0.f};
            s4[s] = __builtin_amdgcn_mfma_f32_16x16x32_bf16(kc[s], qfrag, z, 0, 0, 0);
        }

        // ---- masked fixed-shift softmax (exp2 domain), l accumulates per-lane
        ull sh = mw >> (lg * 4);
        float p[4][4];
#pragma unroll
        for (int s = 0; s < 4; ++s) {
            uint nib = (uint)(sh >> (s * 16)) & 0xFu;
#pragma unroll
            for (int r = 0; r < 4; ++r) {
                float t = s4[s][r] - C2_;
                t = ((nib >> r) & 1u) ? t : -1e30f;
                float pv = exp2f(t);
                p[s][r] = pv;
                l_lane += pv;
            }
        }

        // ---- pack to bf16 pairs: pk[s][r2] covers keys s*16+lg*4+{2r2,2r2+1}
        uint pk[4][2];
#pragma unroll
        for (int s = 0; s < 4; ++s)
#pragma unroll
            for (int r2 = 0; r2 < 2; ++r2) {
                uint r;
                asm("v_cvt_pk_bf16_f32 %0, %1, %2" : "=v"(r) : "v"(p[s][2 * r2]), "v"(p[s][2 * r2 + 1]));
                pk[s][r2] = r;
            }

        // ---- redistribute to P^T B-fragments pt[kstep][j] (keys kstep*32+lg*8+2j,+1)
        uint pt[2][4];
#pragma unroll
        for (int kstep = 0; kstep < 2; ++kstep)
#pragma unroll
            for (int j = 0; j < 4; ++j) {
                int src = (j >> 1) ? src1 : src0;
                uint vA = __shfl(pk[kstep * 2 + 0][j & 1], src, 64);
                uint vB = __shfl(pk[kstep * 2 + 1][j & 1], src, 64);
                pt[kstep][j] = hiHalf ? vB : vA;
            }

        // ---- PV: O^T[d][q] = mfma(A=V^T, B=P^T); acc0 d=0..15, acc1 d=16..31
#pragma unroll
        for (int kstep = 0; kstep < 2; ++kstep) {
            union { uint u[4]; bf16x8 v; } cvt;
            cvt.u[0] = pt[kstep][0]; cvt.u[1] = pt[kstep][1];
            cvt.u[2] = pt[kstep][2]; cvt.u[3] = pt[kstep][3];
            acc0 = __builtin_amdgcn_mfma_f32_16x16x32_bf16(vc[kstep], cvt.v, acc0, 0, 0, 0);
            acc1 = __builtin_amdgcn_mfma_f32_16x16x32_bf16(vc[2 + kstep], cvt.v, acc1, 0, 0, 0);
        }

        // advance
        kp += 64 * DK_;
        vp += 64;
        mp += T_;
#pragma unroll
        for (int s = 0; s < 4; ++s) kc[s] = kn[s];
        mw = mn;
    }

    // ---- l: reduce across key-owning lane groups (lane bits 4,5)
    l_lane += __shfl_xor(l_lane, 16, 64);
    l_lane += __shfl_xor(l_lane, 32, 64);

    // ---- write partials: lane holds O^T[d=lg*4+r (+16)][q=lr] -> float4 stores
    size_t obase = (((size_t)kh * B_ + b) * H_ + h) * T_ + qt * 64;
    int qloc = w * 16 + lr;
    *(f32x4*)(Opart + (obase + qloc) * DK_ + lg * 4) = acc0;
    *(f32x4*)(Opart + (obase + qloc) * DK_ + 16 + lg * 4) = acc1;
    if (lg == 0) Lpart[obase + qloc] = l_lane;
}

// ------------------------------------ merge split-K partials (plain sums) -> ctx
__global__ __launch_bounds__(256) void merge_kernel(
    const float* __restrict__ Opart, const float* __restrict__ Lpart,
    float* __restrict__ ctx) {
    int idx = blockIdx.x * 256 + threadIdx.x;  // B*H*T*32 total
    int d = idx & 31;
    int t = (idx >> 5) & (T_ - 1);
    int bh = idx >> 14;
    int h = bh & 7, b = bh >> 3;
    size_t ps = (size_t)B_ * H_ * T_;
    size_t base = (size_t)bh * T_ + t;
    float L = 0.f, o = 0.f;
#pragma unroll
    for (int s = 0; s < SPLIT_; ++s) {
        L += Lpart[s * ps + base];
        o += Opart[(s * ps + base) * DK_ + d];
    }
    ctx[((size_t)b * T_ + t) * D_ + h * DK_ + d] = o / L;
}

// ------------------------------------------------ out = xq + ctx@Wo + bo
__global__ __launch_bounds__(256) void out_kernel(
    const float* __restrict__ ctx, const float* __restrict__ xq,
    const float* __restrict__ Wo, const float* __restrict__ bo, float* __restrict__ out) {
    int blk = blockIdx.x;
    int t0 = (blk & 31) * 16;
    int b = blk >> 5;
    int tid = threadIdx.x;
    __shared__ float s_c[16][D_];
    for (int r = 0; r < 16; ++r)
        s_c[r][tid] = ctx[((size_t)b * T_ + t0 + r) * D_ + tid];
    __syncthreads();
    float acc[16];
#pragma unroll
    for (int r = 0; r < 16; ++r) acc[r] = bo[tid];
    for (int e = 0; e < D_; ++e) {
        float w = Wo[e * D_ + tid];
#pragma unroll
        for (int r = 0; r < 16; ++r) acc[r] += s_c[r][e] * w;
    }
    for (int r = 0; r < 16; ++r) {
        size_t off = ((size_t)b * T_ + t0 + r) * D_ + tid;
        out[off] = xq[off] + acc[r];
    }
}

// ---------------------------------------------------------------- launcher
extern "C" void kernel_launch(void* const* d_in, const int* in_sizes, int n_in,
                              void* d_out, int out_size, void* d_ws, size_t ws_size,
                              hipStream_t stream) {
    const float* x = (const float*)d_in[0];
    const float* md = (const float*)d_in[1];
    const float* na = (const float*)d_in[2];
    const float* ea = (const float*)d_in[3];
    const int* mask = (const int*)d_in[4];
    const float* W_ts1 = (const float*)d_in[5];
    const float* b_ts1 = (const float*)d_in[6];
    const float* W_ts2 = (const float*)d_in[7];
    const float* b_ts2 = (const float*)d_in[8];
    const float* W_a1 = (const float*)d_in[9];
    const float* b_a1 = (const float*)d_in[10];
    const float* W_a2 = (const float*)d_in[11];
    const float* b_a2 = (const float*)d_in[12];
    const float* W_e1 = (const float*)d_in[13];
    const float* b_e1 = (const float*)d_in[14];
    const float* W_e2 = (const float*)d_in[15];
    const float* b_e2 = (const float*)d_in[16];
    const float* Wq = (const float*)d_in[17];
    const float* bq = (const float*)d_in[18];
    const float* Wk = (const float*)d_in[19];
    const float* bk = (const float*)d_in[20];
    const float* Wv = (const float*)d_in[21];
    const float* bv = (const float*)d_in[22];
    const float* Wo = (const float*)d_in[23];
    const float* bo = (const float*)d_in[24];
    const float* ln_g = (const float*)d_in[25];
    const float* ln_b = (const float*)d_in[26];
    float* out = (float*)d_out;

    char* ws = (char*)d_ws;
    float* pe = (float*)ws;    ws += (size_t)T_ * D_ * 4;
    ull* bitsT = (ull*)ws;     ws += (size_t)B_ * KWORDS_ * T_ * 8;
    __bf16* Kb = (__bf16*)ws;  ws += (size_t)B_ * H_ * NT_ * DK_ * 2;
    __bf16* Vt = (__bf16*)ws;  ws += (size_t)B_ * H_ * DK_ * NT_ * 2;
    float* xq = (float*)ws;    ws += (size_t)B_ * T_ * D_ * 4;
    __bf16* Qb = (__bf16*)ws;  ws += (size_t)B_ * T_ * D_ * 2;
    float* ctx = (float*)ws;   ws += (size_t)B_ * T_ * D_ * 4;
    float* Opart = (float*)ws; ws += (size_t)SPLIT_ * B_ * H_ * T_ * DK_ * 4;
    float* Lpart = (float*)ws; ws += (size_t)SPLIT_ * B_ * H_ * T_ * 4;
    // bf16 prepped weights
    __bf16* ts1P = (__bf16*)ws; ws += 6144 * 2;
    __bf16* a1P = (__bf16*)ws;  ws += 2048 * 2;
    __bf16* e1P = (__bf16*)ws;  ws += 8192 * 2;
    __bf16* ts2T = (__bf16*)ws; ws += 36864 * 2;
    __bf16* a2T = (__bf16*)ws;  ws += 4096 * 2;
    __bf16* e2T = (__bf16*)ws;  ws += 65536 * 2;
    __bf16* WkT = (__bf16*)ws;  ws += 65536 * 2;
    __bf16* WvT = (__bf16*)ws;  ws += 65536 * 2;

    pe_kernel<<<T_, 256, 0, stream>>>(pe);
    maskbits_kernel<<<B_ * T_, 256, 0, stream>>>(mask, bitsT);
    wprep_kernel<<<992, 256, 0, stream>>>(W_ts1, W_a1, W_e1, W_ts2, W_a2, W_e2, Wk, Wv,
                                          ts1P, a1P, e1P, ts2T, a2T, e2T, WkT, WvT);
    kv_mfma_kernel<<<B_ * N_ * (T_ / 64), 256, 0, stream>>>(
        md, na, ea, ts1P, a1P, e1P, b_ts1, b_a1, b_e1,
        ts2T, a2T, e2T, b_ts2, b_a2, b_e2, WkT, bk, WvT, bv, pe, Kb, Vt);
    q_kernel<<<B_ * (T_ / 16), 256, 0, stream>>>(x, pe, Wq, bq, ln_g, ln_b, xq, Qb);
    attn_mfma_kernel<<<B_ * H_ * (T_ / 64) * SPLIT_, 256, 0, stream>>>(
        Qb, Kb, Vt, bitsT, Opart, Lpart);
    merge_kernel<<<(B_ * H_ * T_ * DK_) / 256, 256, 0, stream>>>(Opart, Lpart, ctx);
    out_kernel<<<B_ * (T_ / 16), 256, 0, stream>>>(ctx, xq, Wo, bo, out);
}